// Round 7
// baseline (279.184 us; speedup 1.0000x reference)
//
#include <hip/hip_runtime.h>
#include <math.h>

#define H_N 1024
#define M_N 8
#define HM 8192

typedef float f32x4 __attribute__((ext_vector_type(4)));

static __device__ __forceinline__ float log_eps(float x) {
    const float EPS_TINY = 1.17549435e-38f;
    return __logf(x <= 0.0f ? EPS_TINY : x);
}

// ---------------- kernel 1: pbuf[ic][j] = sum_{i in chunk ic} w[i][j] * o[i] -------
// grid = 8 * nic blocks; chunk = HM/nic rows. No atomics, coalesced dwordx4 out.
__global__ __launch_bounds__(256) void gemv_partial(const float* __restrict__ w,
                                                    const float* __restrict__ o,
                                                    float* __restrict__ pbuf,
                                                    int rows_per_chunk) {
    const int jb = blockIdx.x & 7;   // 8 j-blocks of 1024 columns
    const int ic = blockIdx.x >> 3;  // nic i-chunks
    const int j0 = jb * 1024 + threadIdx.x * 4;
    const int i0 = ic * rows_per_chunk;
    f32x4 acc = {0.f, 0.f, 0.f, 0.f};
    const float* wp = w + (size_t)i0 * HM + j0;
#pragma unroll 4
    for (int i = 0; i < rows_per_chunk; ++i) {
        const float ov = o[i0 + i];
        const f32x4 wv = *reinterpret_cast<const f32x4*>(wp);
        acc.x += wv.x * ov; acc.y += wv.y * ov; acc.z += wv.z * ov; acc.w += wv.w * ov;
        wp += HM;
    }
    *reinterpret_cast<f32x4*>(&pbuf[(size_t)ic * HM + j0]) = acc;
}

// ---------------- kernel 2: thread-per-COLUMN state update (fully coalesced) -------
// 8192 threads; softmax over 8-lane groups via __shfl_xor (masks 1,2,4).
__global__ __launch_bounds__(256) void row_kernel(
    const float* __restrict__ x, const float* __restrict__ s,
    const float* __restrict__ a, const float* __restrict__ zi,
    const float* __restrict__ zj, const float* __restrict__ p,
    const float* __restrict__ pi, const float* __restrict__ pj,
    const float* __restrict__ b, const float* __restrict__ noise,
    const float* __restrict__ ga, const float* __restrict__ gw,
    const float* __restrict__ gb, const float* __restrict__ gs,
    const float* __restrict__ k, const float* __restrict__ pbuf,
    int nic, float* __restrict__ out) {
    const int j = blockIdx.x * blockDim.x + threadIdx.x;   // 0..HM-1
    if (j >= HM) return;

    const float gwv = gw[0], gav = ga[0], gbv = gb[0], gsv = gs[0], kv = k[0], pv = p[0];
    const float c = kv * 1e-4f;   // k*DT/TP

    float* o_new  = out;
    float* s_new  = out + (size_t)HM;
    float* a_new  = out + (size_t)2 * HM;
    float* zi_new = out + (size_t)3 * HM;
    float* zj_new = out + (size_t)4 * HM;
    float* p_new  = out + (size_t)5 * HM;          // 1 element
    float* pi_new = out + (size_t)5 * HM + 1;
    float* pj_new = out + (size_t)6 * HM + 1;
    float* b_new  = out + (size_t)7 * HM + 1 + (size_t)2 * HM * HM;

    // reduce split-K partials for this column (coalesced across lanes)
    float st = 0.f;
#pragma unroll 8
    for (int ic = 0; ic < nic; ++ic) st += pbuf[(size_t)ic * HM + j];

    const float stv = gwv * (b[j] + st);
    const float sn  = s[j] + 0.02f * (stv - a[j] + log_eps(x[j]) + gsv * noise[j] - s[j]);

    // softmax over the 8 lanes sharing this row (lanes j&~7 .. j|7)
    float mx = sn;
    mx = fmaxf(mx, __shfl_xor(mx, 1));
    mx = fmaxf(mx, __shfl_xor(mx, 2));
    mx = fmaxf(mx, __shfl_xor(mx, 4));
    const float e = __expf(sn - mx);
    float sum = e;
    sum += __shfl_xor(sum, 1);
    sum += __shfl_xor(sum, 2);
    sum += __shfl_xor(sum, 4);
    const float on = e / sum;

    const float an  = a[j]  + (float)(0.001 / 2.7)  * (gav * on - a[j]);
    const float zin = zi[j] + (float)(0.001 / 0.24) * (on - zi[j]);
    const float zjn = zj[j] + (float)(0.001 / 0.24) * (on - zj[j]);
    const float pin = pi[j] + c * (zin - pi[j]);
    const float pjn = pj[j] + c * (zjn - pj[j]);

    o_new[j]  = on;
    s_new[j]  = sn;
    a_new[j]  = an;
    zi_new[j] = zin;
    zj_new[j] = zjn;
    pi_new[j] = pin;
    pj_new[j] = pjn;
    b_new[j]  = gbv * log_eps(pjn);
    if (j == 0) p_new[0] = pv + c * (1.0f - pv);
}

// ---------------- kernel 3: pij_new + w_new (R6 body + unroll 2) -------------------
__global__ __launch_bounds__(256) void outer_kernel(
    const float* __restrict__ pij, const float* __restrict__ out_ro,
    float* __restrict__ out, const float* __restrict__ p,
    const float* __restrict__ k) {
    const float* zi_new = out_ro + (size_t)3 * HM;
    const float* zj_new = out_ro + (size_t)4 * HM;
    const float* pi_new = out_ro + (size_t)5 * HM + 1;
    const float* pj_new = out_ro + (size_t)6 * HM + 1;
    float* pij_new = out + (size_t)7 * HM + 1;
    float* w_new   = pij_new + (size_t)HM * HM;

    const float kv = k[0], pv = p[0];
    const float c  = kv * 1e-4f;
    const float pn = pv + c * (1.0f - pv);

    const size_t nvec   = (size_t)HM * HM / 4;
    const size_t stride = (size_t)gridDim.x * blockDim.x;
#pragma unroll 2
    for (size_t v = (size_t)blockIdx.x * blockDim.x + threadIdx.x; v < nvec; v += stride) {
        const size_t idx = v * 4;
        const int I = (int)(idx >> 13);
        const int J = (int)(idx & 8191);
        const float ziI = zi_new[I];
        const float piI = pi_new[I];
        const f32x4 pv4 = *reinterpret_cast<const f32x4*>(&pij[idx]);
        const float zj0 = zj_new[J + 0], zj1 = zj_new[J + 1], zj2 = zj_new[J + 2], zj3 = zj_new[J + 3];
        const float pj0 = pj_new[J + 0], pj1 = pj_new[J + 1], pj2 = pj_new[J + 2], pj3 = pj_new[J + 3];

        const float q0 = pv4.x + c * (ziI * zj0 - pv4.x);
        const float q1 = pv4.y + c * (ziI * zj1 - pv4.y);
        const float q2 = pv4.z + c * (ziI * zj2 - pv4.z);
        const float q3 = pv4.w + c * (ziI * zj3 - pv4.w);

        pij_new[idx + 0] = q0;
        pij_new[idx + 1] = q1;
        pij_new[idx + 2] = q2;
        pij_new[idx + 3] = q3;

        const float v0 = __fdividef(pn * q0, piI * pj0);
        const float v1 = __fdividef(pn * q1, piI * pj1);
        const float v2 = __fdividef(pn * q2, piI * pj2);
        const float v3 = __fdividef(pn * q3, piI * pj3);

        w_new[idx + 0] = log_eps(v0);
        w_new[idx + 1] = log_eps(v1);
        w_new[idx + 2] = log_eps(v2);
        w_new[idx + 3] = log_eps(v3);
    }
}

extern "C" void kernel_launch(void* const* d_in, const int* in_sizes, int n_in,
                              void* d_out, int out_size, void* d_ws, size_t ws_size,
                              hipStream_t stream) {
    const float* x     = (const float*)d_in[0];
    const float* s     = (const float*)d_in[1];
    const float* o     = (const float*)d_in[2];
    const float* a     = (const float*)d_in[3];
    const float* zi    = (const float*)d_in[4];
    const float* zj    = (const float*)d_in[5];
    const float* p     = (const float*)d_in[6];
    const float* pi    = (const float*)d_in[7];
    const float* pj    = (const float*)d_in[8];
    const float* pij   = (const float*)d_in[9];
    const float* b     = (const float*)d_in[10];
    const float* w     = (const float*)d_in[11];
    const float* noise = (const float*)d_in[12];
    const float* ga    = (const float*)d_in[13];
    const float* gw    = (const float*)d_in[14];
    const float* gb    = (const float*)d_in[15];
    const float* gs    = (const float*)d_in[16];
    const float* k     = (const float*)d_in[17];

    float* out  = (float*)d_out;
    float* pbuf = (float*)d_ws;

    // split-K depth limited by available workspace (deterministic per session)
    int nic;
    if      (ws_size >= (size_t)256 * HM * sizeof(float)) nic = 256;  // 8 MB
    else if (ws_size >= (size_t)128 * HM * sizeof(float)) nic = 128;  // 4 MB
    else                                                  nic = 64;   // 2 MB (R6-proven)
    const int rpc = HM / nic;

    gemv_partial<<<8 * nic, 256, 0, stream>>>(w, o, pbuf, rpc);
    row_kernel<<<HM / 256, 256, 0, stream>>>(
        x, s, a, zi, zj, p, pi, pj, b, noise, ga, gw, gb, gs, k, pbuf, nic, out);
    outer_kernel<<<2048, 256, 0, stream>>>(pij, out, out, p, k);
}